// Round 1
// 712.901 us; speedup vs baseline: 1.1857x; 1.1857x over previous
//
#include <hip/hip_runtime.h>

#define HH 384
#define WW 384
#define HWSZ (HH * WW)
#define NIMG 24

__device__ __forceinline__ int refl(int i, int n) {
    if (i < 0) i = -i;
    if (i >= n) i = 2 * n - 2 - i;
    return i;
}

// 5-tap Gaussian (sigma=1, normalized), double-precision constants cast to float
__device__ const float LPW[5] = {
    0.054488684549642945f, 0.24420134200323332f, 0.40261994689424746f,
    0.24420134200323332f, 0.054488684549642945f
};

// ---------------- filter generation (on device, fp64, matches numpy) -------
__global__ __launch_bounds__(256) void gen_filters(float* __restrict__ filt) {
    int f = blockIdx.x;  // 0..27
    int s, d, nd, off;
    if (f < 4)       { s = 0; nd = 4;  d = f;      off = 0;    }
    else if (f < 12) { s = 1; nd = 8;  d = f - 4;  off = 900;  }
    else             { s = 2; nd = 16; d = f - 12; off = 2700; }

    double angle = M_PI * (double)d / (double)nd;
    double scale = (double)(s + 1);
    double sx = 2.0 * scale, sy = 0.5 * scale;

    int tid = threadIdx.x;
    double val = 0.0;
    if (tid < 225) {
        int row = tid / 15, col = tid % 15;
        double X = (double)(col - 7);
        double Y = (double)(row - 7);
        double ca = cos(angle), sa = sin(angle);
        double Xr = X * ca - Y * sa;
        double Yr = X * sa + Y * ca;
        val = exp(-0.5 * (Xr * Xr / (sx * sx) + Yr * Yr / (sy * sy))) * Xr / (sx * sx);
    }

    __shared__ double red[256];
    red[tid] = val;
    __syncthreads();
    for (int st = 128; st > 0; st >>= 1) {
        if (tid < st) red[tid] += red[tid + st];
        __syncthreads();
    }
    double mean = red[0] / 225.0;
    __syncthreads();

    double dv = (tid < 225) ? (val - mean) : 0.0;
    red[tid] = dv * dv;
    __syncthreads();
    for (int st = 128; st > 0; st >>= 1) {
        if (tid < st) red[tid] += red[tid + st];
        __syncthreads();
    }
    double nrm = sqrt(red[0]);
    double inv = (nrm > 1e-6) ? (1.0 / nrm) : 1.0;

    if (tid < 225) {
        filt[off + d * 225 + tid] = (float)((val - mean) * inv);
    }
}

// ---------------- 5x5 separable Gaussian lowpass, reflect pad --------------
__global__ __launch_bounds__(256) void lp_kernel(
    const float* __restrict__ in, float* __restrict__ out, long ostride) {
    int n = blockIdx.z;
    int x = blockIdx.x * 32 + threadIdx.x;
    int y = blockIdx.y * 8 + threadIdx.y;
    const float* ip = in + (long)n * HWSZ;

    float acc = 0.f;
#pragma unroll
    for (int fy = 0; fy < 5; ++fy) {
        int yy = refl(y + fy - 2, HH);
        const float* rp = ip + yy * WW;
        float rs = 0.f;
#pragma unroll
        for (int fx = 0; fx < 5; ++fx) {
            int xx = refl(x + fx - 2, WW);
            rs = fmaf(LPW[fx], rp[xx], rs);
        }
        acc = fmaf(LPW[fy], rs, acc);
    }
    out[(long)n * ostride + y * WW + x] = acc;
}

// ---------------- directional 15x15 bank, reflect pad ----------------------
// band = A[n] - B[n] computed on the fly; all ND directions in registers.
//
// Every oriented filter is exactly point-antisymmetric: F[14-i][14-j] = -F[i][j]
// (raw kernel k(-X,-Y) = -k(X,Y); mean is ~0 and normalization is symmetric),
// and F[7][7] = 0. So:
//   out_d = sum over 112 half-window positions of F_d[7+u][7+v] * Delta(u,v)
// with Delta(u,v) = p[y+u][x+v] - p[y-u][x-v], shared across ALL directions.
// This halves the FMA count vs. the full 225-tap correlation.
template <int ND>
__global__ __launch_bounds__(256) void dir_kernel(
    const float* __restrict__ A, long as,
    const float* __restrict__ B, long bs,
    const float* __restrict__ filt,
    float* __restrict__ out, int c0) {
    __shared__ float sm[46][48];

    int n = blockIdx.z;
    int tx = threadIdx.x, ty = threadIdx.y;
    int bx = blockIdx.x * 32, by = blockIdx.y * 32;

    const float* Ab = A + (long)n * as;
    const float* Bb = B + (long)n * bs;

    int lid = ty * 32 + tx;
    for (int l = lid; l < 46 * 46; l += 256) {
        int ly = l / 46, lx = l % 46;
        int gy = refl(by + ly - 7, HH);
        int gx = refl(bx + lx - 7, WW);
        long gi = (long)gy * WW + gx;
        sm[ly][lx] = Ab[gi] - Bb[gi];
    }
    __syncthreads();

    float acc[ND][4];
#pragma unroll
    for (int d = 0; d < ND; ++d)
#pragma unroll
        for (int r = 0; r < 4; ++r) acc[d][r] = 0.f;

    int xc = tx + 7;

    // center row half (u = 0, v = 1..7): F[7][7+v] * (p[y][x+v] - p[y][x-v])
#pragma unroll
    for (int v = 1; v <= 7; ++v) {
        float d0 = sm[ty + 7][xc + v]  - sm[ty + 7][xc - v];
        float d1 = sm[ty + 15][xc + v] - sm[ty + 15][xc - v];
        float d2 = sm[ty + 23][xc + v] - sm[ty + 23][xc - v];
        float d3 = sm[ty + 31][xc + v] - sm[ty + 31][xc - v];
#pragma unroll
        for (int d = 0; d < ND; ++d) {
            float c = filt[d * 225 + 7 * 15 + 7 + v];  // wave-uniform -> s_load
            acc[d][0] = fmaf(c, d0, acc[d][0]);
            acc[d][1] = fmaf(c, d1, acc[d][1]);
            acc[d][2] = fmaf(c, d2, acc[d][2]);
            acc[d][3] = fmaf(c, d3, acc[d][3]);
        }
    }

    // lower half rows (u = 1..7, v = -7..7):
    //   F[7+u][7+v] * (p[y+u][x+v] - p[y-u][x-v])
    for (int u = 1; u <= 7; ++u) {
#pragma unroll
        for (int v = -7; v <= 7; ++v) {
            float d0 = sm[ty + 7 + u][xc + v]  - sm[ty + 7 - u][xc - v];
            float d1 = sm[ty + 15 + u][xc + v] - sm[ty + 15 - u][xc - v];
            float d2 = sm[ty + 23 + u][xc + v] - sm[ty + 23 - u][xc - v];
            float d3 = sm[ty + 31 + u][xc + v] - sm[ty + 31 - u][xc - v];
#pragma unroll
            for (int d = 0; d < ND; ++d) {
                float c = filt[d * 225 + (7 + u) * 15 + (7 + v)];
                acc[d][0] = fmaf(c, d0, acc[d][0]);
                acc[d][1] = fmaf(c, d1, acc[d][1]);
                acc[d][2] = fmaf(c, d2, acc[d][2]);
                acc[d][3] = fmaf(c, d3, acc[d][3]);
            }
        }
    }

    long ob = ((long)n * 29 + c0) * HWSZ;
#pragma unroll
    for (int d = 0; d < ND; ++d) {
#pragma unroll
        for (int r = 0; r < 4; ++r) {
            int y = by + ty + r * 8;
            out[ob + (long)d * HWSZ + (long)y * WW + bx + tx] = acc[d][r];
        }
    }
}

extern "C" void kernel_launch(void* const* d_in, const int* in_sizes, int n_in,
                              void* d_out, int out_size, void* d_ws, size_t ws_size,
                              hipStream_t stream) {
    const float* x = (const float*)d_in[0];
    float* out = (float*)d_out;
    float* ws = (float*)d_ws;

    float* filt = ws;                       // 6300 floats (28 x 225)
    float* lp0 = ws + 6400;                 // 24 * HWSZ
    float* lp1 = lp0 + (long)NIMG * HWSZ;   // 24 * HWSZ

    gen_filters<<<28, 256, 0, stream>>>(filt);

    dim3 blk(32, 8);
    dim3 lpgrid(12, 48, NIMG);
    // lp0 = LP(x); lp1 = LP(lp0); lp2 = LP(lp1) -> out channel 28
    lp_kernel<<<lpgrid, blk, 0, stream>>>(x, lp0, HWSZ);
    lp_kernel<<<lpgrid, blk, 0, stream>>>(lp0, lp1, HWSZ);
    lp_kernel<<<lpgrid, blk, 0, stream>>>(lp1, out + 28l * HWSZ, 29l * HWSZ);

    dim3 dgrid(12, 12, NIMG);
    // band0 = x - lp0      -> channels 0..3
    dir_kernel<4><<<dgrid, blk, 0, stream>>>(x, HWSZ, lp0, HWSZ, filt, out, 0);
    // band1 = lp0 - lp1    -> channels 4..11
    dir_kernel<8><<<dgrid, blk, 0, stream>>>(lp0, HWSZ, lp1, HWSZ, filt + 900, out, 4);
    // band2 = lp1 - lp2    -> channels 12..27  (lp2 lives at out ch 28)
    dir_kernel<16><<<dgrid, blk, 0, stream>>>(lp1, HWSZ, out + 28l * HWSZ, 29l * HWSZ,
                                              filt + 2700, out, 12);
}